// Round 14
// baseline (470.445 us; speedup 1.0000x reference)
//
#include <hip/hip_runtime.h>

#define NWIN 1000
#define WIN  500
#define HID  30
#define ANC  7
#define BATCH 64
#define KS   75
#define PADH 37
#define OBASE_ELEMS (BATCH*ANC*NWIN*2)   // 896000

// k1 geometry: 21 chunks of 24 positions (504 padded; 500 real)
#define CK   24
#define NCK  21

// LDS float-offset map (flat array; epilogue overlays the front)
//   x [buf][c][24 pos][68]  : buf*3264 + (c*24+p)*68 + b     [0 .. 6527]
//   W [buf][24 pos][32]     : 6528 + buf*768 + p*32 + j      [6528 .. 8063]
//   hs[ph][64 b][61]        : (ph*64+b)*61 + col  (overlay)  [0 .. 7807]
#define XB(buf,c,p,b) ((buf)*3264 + ((c)*24+(p))*68 + (b))
#define WB(buf,p,j)   (6528 + (buf)*768 + (p)*32 + (j))
#define HS(ph,b,col)  (((ph)*64+(b))*61 + (col))

__device__ __forceinline__ void gload_lds16(const float* g, float* l) {
    __builtin_amdgcn_global_load_lds(
        (const __attribute__((address_space(1))) void*)g,
        (__attribute__((address_space(3))) void*)l, 16, 0, 0);
}

// ---------------------------------------------------------------------------
// Kernel 1 (v12): v6 structure (best known: 159us) with ONE change --
// __launch_bounds__(256, 3): raises the resident-waves/SIMD cap 2 -> 3
// (empirical law from R3..R12: 2nd arg w caps waves/SIMD at w AND sets
// regalloc budget ~512/w; v6's 112 VGPR fits the w=3 budget of ~170).
// Plus the v10 W-clamp correctness fix (row clamp, not byte clamp).
// lane = (bq 0..15, jq 0..3): acc[4 b][8 j][2 c]; per position one wave reads
// 2 b128 x + 2 b128 W for 64 FMA. W via global_load_lds into padded [24][32];
// x reg-staged as 3 float4/thread, issued before compute, committed after.
// ---------------------------------------------------------------------------
__global__ __launch_bounds__(256, 3) void k1(
        const float* __restrict__ x,
        const float* __restrict__ W1, const float* __restrict__ b1,
        const float* __restrict__ W2, const float* __restrict__ b2,
        float* __restrict__ out_base)
{
    __shared__ float smem[8064];   // 32,256 B

    const int n    = blockIdx.x;
    const int t    = threadIdx.x;
    const int wid  = __builtin_amdgcn_readfirstlane(t >> 6);
    const int lane = t & 63;
    const int bq   = lane & 15;        // 4-batch group
    const int jq   = lane >> 4;        // j-quarter
    const int b0   = bq * 4;
    const int j0   = jq * 8;

    float acc[4][8][2];
#pragma unroll
    for (int i = 0; i < 4; ++i)
#pragma unroll
        for (int j = 0; j < 8; ++j) { acc[i][j][0] = 0.f; acc[i][j][1] = 0.f; }

    // x staging: granule = float4 = 2 positions x 2 channels.
    // 64 b * 12 granules = 768 per chunk -> exactly 3 per thread.
    int sb[3], sq[3];
#pragma unroll
    for (int r = 0; r < 3; ++r) {
        const int idx = t + r * 256;
        sb[r] = idx / 12;
        sq[r] = idx % 12;
    }

    const float4* __restrict__ x4 = reinterpret_cast<const float4*>(x);
    float4 xr[3];

    auto issue_x = [&](int ck) {
#pragma unroll
        for (int r = 0; r < 3; ++r) {
            int gq = ck * 12 + sq[r];          // float4 index within window row
            if (gq > 249) gq = 249;            // last-chunk OOB clamp
            xr[r] = x4[(size_t)sb[r] * 250000u + (size_t)n * 250u + gq];
        }
    };

    auto commit_x = [&](int buf, int ck) {
#pragma unroll
        for (int r = 0; r < 3; ++r) {
            const int p0 = 2 * sq[r], p1 = p0 + 1;
            const bool ok0 = (ck * CK + p0) < 500;
            const bool ok1 = (ck * CK + p1) < 500;
            const int bb = sb[r];
            smem[XB(buf, 0, p0, bb)] = ok0 ? fmaf(2.f, xr[r].x, -1.f) : 0.f;
            smem[XB(buf, 1, p0, bb)] = ok0 ? fmaf(2.f, xr[r].y, -1.f) : 0.f;
            smem[XB(buf, 0, p1, bb)] = ok1 ? fmaf(2.f, xr[r].z, -1.f) : 0.f;
            smem[XB(buf, 1, p1, bb)] = ok1 ? fmaf(2.f, xr[r].w, -1.f) : 0.f;
        }
    };

    // W chunk: 24 rows x 30 floats -> 192 16B granules into padded [24][32].
    // ROW clamp only (v10 fix): tail rows' junk multiplies zeroed x positions;
    // row straddle (floats 30,31) lands in pad slots. The final granule of
    // window 999 reads 8B past the 60MB array -- within page slack (2304B).
    auto issue_w = [&](int ck, int buf) {
        if (t < 192) {
            int gp = ck * CK + (t >> 3);
            if (gp > 499) gp = 499;
            const size_t off = (size_t)n * 15000u + (size_t)gp * 30u
                             + (size_t)(t & 7) * 4u;
            gload_lds16(W1 + off, &smem[WB(buf, 0, 0) + (t & 192) * 4]);
        }
    };

    // ---- prologue ------------------------------------------------------
    issue_w(0, 0);
    issue_x(0);
    commit_x(0, 0);
    __syncthreads();

    // ---- main loop: 1 barrier per chunk --------------------------------
    for (int ck = 0; ck < NCK; ++ck) {
        const int cur = ck & 1, nxt = cur ^ 1;
        const bool pre = (ck < NCK - 1);
        if (pre) {
            issue_w(ck + 1, nxt);
            issue_x(ck + 1);
            __builtin_amdgcn_sched_barrier(0);   // pin issues before compute
        }

        const int pb = wid * 6;
#pragma unroll
        for (int i = 0; i < 6; ++i) {
            const int p = pb + i;
            const float4 xa = *reinterpret_cast<const float4*>(&smem[XB(cur, 0, p, b0)]);
            const float4 xb = *reinterpret_cast<const float4*>(&smem[XB(cur, 1, p, b0)]);
            const float4 w0 = *reinterpret_cast<const float4*>(&smem[WB(cur, p, j0)]);
            const float4 w1 = *reinterpret_cast<const float4*>(&smem[WB(cur, p, j0 + 4)]);
            const float xav[4] = {xa.x, xa.y, xa.z, xa.w};
            const float xbv[4] = {xb.x, xb.y, xb.z, xb.w};
            const float wv[8]  = {w0.x, w0.y, w0.z, w0.w, w1.x, w1.y, w1.z, w1.w};
#pragma unroll
            for (int ii = 0; ii < 4; ++ii)
#pragma unroll
                for (int jj = 0; jj < 8; ++jj) {
                    acc[ii][jj][0] = fmaf(xav[ii], wv[jj], acc[ii][jj][0]);
                    acc[ii][jj][1] = fmaf(xbv[ii], wv[jj], acc[ii][jj][1]);
                }
        }

        if (pre) commit_x(nxt, ck + 1);          // vmcnt waits (covered)
        __syncthreads();                         // drains gload_lds too
    }

    // ---- epilogue: reduce 4 wave-partials into hs[0] + hs[1] ------------
    if (wid < 2) {
#pragma unroll
        for (int ii = 0; ii < 4; ++ii)
#pragma unroll
            for (int jj = 0; jj < 8; ++jj) {
                const int j = j0 + jj;
                if (j < 30) {
                    smem[HS(wid, b0 + ii, j)]      = acc[ii][jj][0];
                    smem[HS(wid, b0 + ii, 30 + j)] = acc[ii][jj][1];
                }
            }
    }
    __syncthreads();
    if (wid >= 2) {
#pragma unroll
        for (int ii = 0; ii < 4; ++ii)
#pragma unroll
            for (int jj = 0; jj < 8; ++jj) {
                const int j = j0 + jj;
                if (j < 30) {
                    smem[HS(wid - 2, b0 + ii, j)]      += acc[ii][jj][0];
                    smem[HS(wid - 2, b0 + ii, 30 + j)] += acc[ii][jj][1];
                }
            }
    }
    __syncthreads();

    {   // bias + relu + two-pass batch stats (64-lane butterflies) + normalize
        const int bb = t & 63;
        const int q2 = t >> 6;
        const int ch = q2 >> 1;
        const int jh = (q2 & 1) * 15;
        const float* __restrict__ b1p = b1 + n * HID + jh;
#pragma unroll
        for (int jj = 0; jj < 15; ++jj) {
            const int col = ch * 30 + jh + jj;
            float v = smem[HS(0, bb, col)] + smem[HS(1, bb, col)] + b1p[jj];
            v = fmaxf(v, 0.f);
            float s = v;
#pragma unroll
            for (int off = 32; off > 0; off >>= 1) s += __shfl_xor(s, off);
            const float mean = s * (1.f / 64.f);
            const float d = v - mean;
            float ss = d * d;
#pragma unroll
            for (int off = 32; off > 0; off >>= 1) ss += __shfl_xor(ss, off);
            const float var = ss * (1.f / 64.f);
            const float rn  = rsqrtf(var + 1e-5f);
            smem[HS(0, bb, col)] = d * rn;
        }
    }
    __syncthreads();

    // ---- GEMM2 + write out_base[b][a][n][c] -----------------------------
    const float* __restrict__ w2p = W2 + (size_t)n * (HID * ANC);
    float2* __restrict__ ob2 = reinterpret_cast<float2*>(out_base);
    for (int idx = t; idx < BATCH * ANC; idx += 256) {
        const int bb = idx / 7, a = idx - bb * 7;
        float o0 = b2[n * ANC + a], o1 = o0;
#pragma unroll
        for (int h = 0; h < HID; ++h) {
            const float wv = w2p[h * ANC + a];
            o0 = fmaf(smem[HS(0, bb, h)],      wv, o0);
            o1 = fmaf(smem[HS(0, bb, 30 + h)], wv, o1);
        }
        ob2[((size_t)bb * ANC + a) * NWIN + n] = make_float2(o0, o1);
    }
}

// ---------------------------------------------------------------------------
// Kernel 2: softmax over ANC + reflect-pad + conv (2 needed output columns)
// via sum/diff factorization. (256,2): 112-reg budget, no spill.
// ---------------------------------------------------------------------------
__global__ __launch_bounds__(256, 2) void k2(
        const float* __restrict__ out_base,
        const float* __restrict__ conv_w, const float* __restrict__ conv_b,
        float* __restrict__ out_smooth)
{
    __shared__ float2 sdl[199 * ANC];
    __shared__ float2 wael[ANC * ANC * KS];

    const int bidx = blockIdx.x;
    const int b  = bidx >> 3;
    const int ht = bidx & 7;
    const int h0 = ht * 125;
    const int t  = threadIdx.x;

    const float2* __restrict__ cw2 = reinterpret_cast<const float2*>(conv_w);
    for (int idx = t; idx < ANC * ANC * KS; idx += 256) {
        const float2 w = cw2[idx];
        wael[idx] = make_float2(w.x + w.y, w.x - w.y);
    }

    if (t < 199) {
        const int hglob = h0 - PADH + t;
        const int hm = hglob < 0 ? -hglob
                     : (hglob >= NWIN ? 2 * NWIN - 2 - hglob : hglob);
        float p[2][ANC];
#pragma unroll
        for (int c = 0; c < 2; ++c) {
            float v[ANC];
            float m = -1e30f;
#pragma unroll
            for (int a = 0; a < ANC; ++a) {
                v[a] = out_base[(((size_t)b * ANC + a) * NWIN + hm) * 2 + c];
                m = fmaxf(m, v[a]);
            }
            float s = 0.f;
#pragma unroll
            for (int a = 0; a < ANC; ++a) { v[a] = __expf(v[a] - m); s += v[a]; }
            const float inv = 1.f / s;
#pragma unroll
            for (int a = 0; a < ANC; ++a) p[c][a] = v[a] * inv;
        }
#pragma unroll
        for (int a = 0; a < ANC; ++a)
            sdl[t * ANC + a] = make_float2(p[0][a] + p[1][a], p[0][a] - p[1][a]);
    }
    __syncthreads();

    for (int idx = t; idx < ANC * 125; idx += 256) {
        const int o  = idx / 125;
        const int hl = idx % 125;
        float sa = 0.f, de = 0.f;
        const float2* __restrict__ wrow = &wael[o * ANC * KS];
#pragma unroll 1
        for (int i = 0; i < ANC; ++i) {
            const float2* __restrict__ sdp = &sdl[hl * ANC + i];
            const float2* __restrict__ wp  = &wrow[i * KS];
#pragma unroll 5
            for (int kh = 0; kh < KS; ++kh) {
                const float2 sd = sdp[kh * ANC];
                const float2 we = wp[kh];
                sa = fmaf(sd.x, we.x, sa);
                de = fmaf(sd.y, we.y, de);
            }
        }
        const float cb = conv_b[o];
        const float o0 = 0.5f * (sa - de) + cb;
        const float o1 = 0.5f * (sa + de) + cb;
        const size_t base = (((size_t)b * ANC + o) * NWIN + (h0 + hl)) * 2;
        out_smooth[base + 0] = o0;
        out_smooth[base + 1] = o1;
    }
}

extern "C" void kernel_launch(void* const* d_in, const int* in_sizes, int n_in,
                              void* d_out, int out_size, void* d_ws, size_t ws_size,
                              hipStream_t stream)
{
    const float* x      = (const float*)d_in[0];
    const float* W1     = (const float*)d_in[1];
    const float* b1     = (const float*)d_in[2];
    const float* W2     = (const float*)d_in[3];
    const float* b2     = (const float*)d_in[4];
    const float* conv_w = (const float*)d_in[5];
    const float* conv_b = (const float*)d_in[6];
    float* out = (float*)d_out;

    k1<<<dim3(NWIN), dim3(256), 0, stream>>>(x, W1, b1, W2, b2, out);
    k2<<<dim3(BATCH * 8), dim3(256), 0, stream>>>(out, conv_w, conv_b,
                                                  out + OBASE_ELEMS);
}

// Round 15
// 260.167 us; speedup vs baseline: 1.8082x; 1.8082x over previous
//
#include <hip/hip_runtime.h>

#define NWIN 1000
#define HID  30
#define ANC  7
#define BATCH 64
#define KS   75
#define PADH 37
#define OBASE_ELEMS (BATCH*ANC*NWIN*2)   // 896000

#define WPITCH 40                         // floats per W row in LDS (160B): 2-way banks, 16B aligned
#define WROWS  504
// hs4 overlay (after the K loop): 4 partial h buffers, pitch 65 (odd -> conflict-free)
#define HS4(k,b,col) ((k)*4160 + (b)*65 + (col))

__device__ __forceinline__ void gload_lds16(const float* g, float* l) {
    __builtin_amdgcn_global_load_lds(
        (const __attribute__((address_space(1))) void*)g,
        (__attribute__((address_space(3))) void*)l, 16, 0, 0);
}

// ---------------------------------------------------------------------------
// Kernel 1 (v13): whole-W-in-LDS, BARRIER-FREE main loop, 16 waves/block.
// Empirical laws R3..R13: launch_bounds 2nd arg w -> VGPR budget ~256/w and
// residency ~w waves/SIMD. 1024-thread block + (1024,4): budget 64, and the
// block itself provides 4 waves/SIMD with no inter-block barrier coupling.
// wave = 4 batches (b0=wid*4); lane = (pg 0..7, jq 0..7): acc[4b][4j][2c]=32.
// Per step (8 positions): 1 ds_read_b128 (W row p, cols jq*4..+3, broadcast
// across batches) + 4 global float2 loads (x, SGPR base + voffset; each
// instruction = one fully-consumed 64B line) + 40 FMA. x double-buffered in
// 16 regs. Census ~58 VGPR <= 64 budget.
// ---------------------------------------------------------------------------
__global__ __launch_bounds__(1024, 4) void k1(
        const float* __restrict__ x,
        const float* __restrict__ W1, const float* __restrict__ b1,
        const float* __restrict__ W2, const float* __restrict__ b2,
        float* __restrict__ out_base)
{
    __shared__ float smem[WROWS * WPITCH];   // 80,640 B -> 1 block/CU

    const int n    = blockIdx.x;
    const int t    = threadIdx.x;
    const int wid  = __builtin_amdgcn_readfirstlane(t >> 6);   // 0..15
    const int lane = t & 63;
    const int pg   = lane & 7;         // position-in-step
    const int jq   = lane >> 3;        // j-quad 0..7
    const int b0   = wid * 4;          // wave's batch base
    const int j0   = jq * 4;

    // ---- x per-batch bases (wave-uniform -> SGPR) -----------------------
    const float2* __restrict__ xb0p = reinterpret_cast<const float2*>(x)
                                      + (size_t)(b0 + 0) * 500000u + (size_t)n * 500u;
    const float2* __restrict__ xb1p = reinterpret_cast<const float2*>(x)
                                      + (size_t)(b0 + 1) * 500000u + (size_t)n * 500u;
    const float2* __restrict__ xb2p = reinterpret_cast<const float2*>(x)
                                      + (size_t)(b0 + 2) * 500000u + (size_t)n * 500u;
    const float2* __restrict__ xb3p = reinterpret_cast<const float2*>(x)
                                      + (size_t)(b0 + 3) * 500000u + (size_t)n * 500u;

    float acc[4][4][2];
#pragma unroll
    for (int i = 0; i < 4; ++i)
#pragma unroll
        for (int j = 0; j < 4; ++j) { acc[i][j][0] = 0.f; acc[i][j][1] = 0.f; }

    float2 xA0, xA1, xA2, xA3, xB0, xB1, xB2, xB3;

#define LDX(V, P) { V##0 = xb0p[P]; V##1 = xb1p[P]; V##2 = xb2p[P]; V##3 = xb3p[P]; }

#define FSTEP(V, P) {                                                         \
    const float4 wf = *reinterpret_cast<const float4*>(&smem[(P) * WPITCH + j0]); \
    const float wv0 = wf.x, wv1 = wf.y, wv2 = wf.z, wv3 = wf.w;               \
    const float2 xv[4] = {V##0, V##1, V##2, V##3};                            \
    _Pragma("unroll")                                                         \
    for (int ii = 0; ii < 4; ++ii) {                                          \
        const float a0 = fmaf(2.f, xv[ii].x, -1.f);                           \
        const float a1 = fmaf(2.f, xv[ii].y, -1.f);                           \
        acc[ii][0][0] = fmaf(a0, wv0, acc[ii][0][0]);                         \
        acc[ii][1][0] = fmaf(a0, wv1, acc[ii][1][0]);                         \
        acc[ii][2][0] = fmaf(a0, wv2, acc[ii][2][0]);                         \
        acc[ii][3][0] = fmaf(a0, wv3, acc[ii][3][0]);                         \
        acc[ii][0][1] = fmaf(a1, wv0, acc[ii][0][1]);                         \
        acc[ii][1][1] = fmaf(a1, wv1, acc[ii][1][1]);                         \
        acc[ii][2][1] = fmaf(a1, wv2, acc[ii][2][1]);                         \
        acc[ii][3][1] = fmaf(a1, wv3, acc[ii][3][1]);                         \
    } }

    // ---- issue first x loads early (independent of LDS) -----------------
    LDX(xA, pg);

    // ---- stage the whole window's W into LDS (once) ---------------------
    // 504 rows x 40-float pitch; granule g (16B) -> row g/10, col4 (g%10)*4.
    // src = row*30 + col (col<=26 exact; col 28 straddles into pads; col>=30
    // junk lands in never-read pad slots). Rows >=500 get junk, zeroed below.
    {
        const float* __restrict__ gw = W1 + (size_t)n * 15000u;
#pragma unroll
        for (int r = 0; r < 5; ++r) {
            const int g = t + r * 1024;
            if (g < 5040) {
                const int row  = g / 10;
                const int col  = (g % 10) * 4;
                const int srow = row < 500 ? row : 499;
                const int scol = col < 28 ? col : 28;
                gload_lds16(gw + srow * 30 + scol,
                            &smem[((t & 0x3C0) + r * 1024) * 4]);
            }
        }
    }
    __syncthreads();                       // drains gload_lds (vmcnt0 at barrier)
    if (t < 160) smem[500 * WPITCH + t] = 0.f;   // zero rows 500..503
    __syncthreads();

    // ---- BARRIER-FREE K loop: 63 steps of 8 positions --------------------
    int p = pg;
    for (int s = 0; s < 60; s += 2) {
        LDX(xB, p + 8);
        FSTEP(xA, p);
        LDX(xA, p + 16);
        FSTEP(xB, p + 8);
        p += 16;
    }
    // p = pg + 480: steps 60, 61, 62
    LDX(xB, p + 8);                        // positions 488+pg (<=495)
    FSTEP(xA, p);                          // step 60
    {
        int pc = p + 16;                   // 496+pg; clamp x (W rows >=500 are 0)
        if (pc > 499) pc = 499;
        LDX(xA, pc);
    }
    FSTEP(xB, p + 8);                      // step 61
    FSTEP(xA, p + 16);                     // step 62: W rows 496..503 (tail zeroed)

#undef LDX
#undef FSTEP

    // ---- reduce pg-pairs in-register, then 4 partials via LDS ------------
#pragma unroll
    for (int ii = 0; ii < 4; ++ii)
#pragma unroll
        for (int jj = 0; jj < 4; ++jj) {
            acc[ii][jj][0] += __shfl_xor(acc[ii][jj][0], 1);
            acc[ii][jj][1] += __shfl_xor(acc[ii][jj][1], 1);
        }
    __syncthreads();                       // everyone done reading W region
    if ((pg & 1) == 0) {
        const int k = pg >> 1;             // 0..3
#pragma unroll
        for (int ii = 0; ii < 4; ++ii)
#pragma unroll
            for (int jj = 0; jj < 4; ++jj) {
                const int j = j0 + jj;
                if (j < 30) {
                    smem[HS4(k, b0 + ii, j)]      = acc[ii][jj][0];
                    smem[HS4(k, b0 + ii, 30 + j)] = acc[ii][jj][1];
                }
            }
    }
    __syncthreads();

    // ---- bias + relu + two-pass batch stats + normalize ------------------
    {
        const int bb = t & 63;
        const int c2 = (t >> 6) & 1;       // wave-uniform
        const int jg = t >> 7;             // 0..7, wave-uniform
#pragma unroll
        for (int k = 0; k < 4; ++k) {
            const int j = jg * 4 + k;
            if (j < 30) {
                const int col = c2 * 30 + j;
                float v = smem[HS4(0, bb, col)] + smem[HS4(1, bb, col)]
                        + smem[HS4(2, bb, col)] + smem[HS4(3, bb, col)]
                        + b1[n * HID + j];
                v = fmaxf(v, 0.f);
                float s = v;
#pragma unroll
                for (int off = 32; off > 0; off >>= 1) s += __shfl_xor(s, off);
                const float mean = s * (1.f / 64.f);
                const float d = v - mean;
                float ss = d * d;
#pragma unroll
                for (int off = 32; off > 0; off >>= 1) ss += __shfl_xor(ss, off);
                const float var = ss * (1.f / 64.f);
                const float rn  = rsqrtf(var + 1e-5f);
                smem[HS4(0, bb, col)] = d * rn;
            }
        }
    }
    __syncthreads();

    // ---- GEMM2 + write out_base[b][a][n][c] ------------------------------
    if (t < BATCH * ANC) {
        const int bb = t / 7, a = t - bb * 7;
        const float* __restrict__ w2p = W2 + (size_t)n * (HID * ANC);
        float o0 = b2[n * ANC + a], o1 = o0;
#pragma unroll
        for (int h = 0; h < HID; ++h) {
            const float wv = w2p[h * ANC + a];
            o0 = fmaf(smem[HS4(0, bb, h)],      wv, o0);
            o1 = fmaf(smem[HS4(0, bb, 30 + h)], wv, o1);
        }
        reinterpret_cast<float2*>(out_base)[((size_t)bb * ANC + a) * NWIN + n]
            = make_float2(o0, o1);
    }
}

// ---------------------------------------------------------------------------
// Kernel 2: softmax over ANC + reflect-pad + conv (2 needed output columns)
// via sum/diff factorization. (256,2): 128-reg budget, no spill.
// ---------------------------------------------------------------------------
__global__ __launch_bounds__(256, 2) void k2(
        const float* __restrict__ out_base,
        const float* __restrict__ conv_w, const float* __restrict__ conv_b,
        float* __restrict__ out_smooth)
{
    __shared__ float2 sdl[199 * ANC];
    __shared__ float2 wael[ANC * ANC * KS];

    const int bidx = blockIdx.x;
    const int b  = bidx >> 3;
    const int ht = bidx & 7;
    const int h0 = ht * 125;
    const int t  = threadIdx.x;

    const float2* __restrict__ cw2 = reinterpret_cast<const float2*>(conv_w);
    for (int idx = t; idx < ANC * ANC * KS; idx += 256) {
        const float2 w = cw2[idx];
        wael[idx] = make_float2(w.x + w.y, w.x - w.y);
    }

    if (t < 199) {
        const int hglob = h0 - PADH + t;
        const int hm = hglob < 0 ? -hglob
                     : (hglob >= NWIN ? 2 * NWIN - 2 - hglob : hglob);
        float p[2][ANC];
#pragma unroll
        for (int c = 0; c < 2; ++c) {
            float v[ANC];
            float m = -1e30f;
#pragma unroll
            for (int a = 0; a < ANC; ++a) {
                v[a] = out_base[(((size_t)b * ANC + a) * NWIN + hm) * 2 + c];
                m = fmaxf(m, v[a]);
            }
            float s = 0.f;
#pragma unroll
            for (int a = 0; a < ANC; ++a) { v[a] = __expf(v[a] - m); s += v[a]; }
            const float inv = 1.f / s;
#pragma unroll
            for (int a = 0; a < ANC; ++a) p[c][a] = v[a] * inv;
        }
#pragma unroll
        for (int a = 0; a < ANC; ++a)
            sdl[t * ANC + a] = make_float2(p[0][a] + p[1][a], p[0][a] - p[1][a]);
    }
    __syncthreads();

    for (int idx = t; idx < ANC * 125; idx += 256) {
        const int o  = idx / 125;
        const int hl = idx % 125;
        float sa = 0.f, de = 0.f;
        const float2* __restrict__ wrow = &wael[o * ANC * KS];
#pragma unroll 1
        for (int i = 0; i < ANC; ++i) {
            const float2* __restrict__ sdp = &sdl[hl * ANC + i];
            const float2* __restrict__ wp  = &wrow[i * KS];
#pragma unroll 5
            for (int kh = 0; kh < KS; ++kh) {
                const float2 sd = sdp[kh * ANC];
                const float2 we = wp[kh];
                sa = fmaf(sd.x, we.x, sa);
                de = fmaf(sd.y, we.y, de);
            }
        }
        const float cb = conv_b[o];
        const float o0 = 0.5f * (sa - de) + cb;
        const float o1 = 0.5f * (sa + de) + cb;
        const size_t base = (((size_t)b * ANC + o) * NWIN + (h0 + hl)) * 2;
        out_smooth[base + 0] = o0;
        out_smooth[base + 1] = o1;
    }
}

extern "C" void kernel_launch(void* const* d_in, const int* in_sizes, int n_in,
                              void* d_out, int out_size, void* d_ws, size_t ws_size,
                              hipStream_t stream)
{
    const float* x      = (const float*)d_in[0];
    const float* W1     = (const float*)d_in[1];
    const float* b1     = (const float*)d_in[2];
    const float* W2     = (const float*)d_in[3];
    const float* b2     = (const float*)d_in[4];
    const float* conv_w = (const float*)d_in[5];
    const float* conv_b = (const float*)d_in[6];
    float* out = (float*)d_out;

    k1<<<dim3(NWIN), dim3(1024), 0, stream>>>(x, W1, b1, W2, b2, out);
    k2<<<dim3(BATCH * 8), dim3(256), 0, stream>>>(out, conv_w, conv_b,
                                                  out + OBASE_ELEMS);
}

// Round 16
// 166.589 us; speedup vs baseline: 2.8240x; 1.5617x over previous
//
#include <hip/hip_runtime.h>

#define NWIN 1000
#define WIN  500
#define HID  30
#define ANC  7
#define BATCH 64
#define KS   75
#define PADH 37
#define OBASE_ELEMS (BATCH*ANC*NWIN*2)   // 896000

// k1 geometry: 21 chunks of 24 positions (504 padded; 500 real)
#define CK   24
#define NCK  21

// LDS float-offset map (flat array; epilogue overlays the front)
//   x [buf][c][24 pos][68]  : buf*3264 + (c*24+p)*68 + b     [0 .. 6527]
//   W [buf][24 pos][32]     : 6528 + buf*768 + p*32 + j      [6528 .. 8063]
//   hs[ph][64 b][61]        : (ph*64+b)*61 + col  (overlay)  [0 .. 7807]
#define XB(buf,c,p,b) ((buf)*3264 + ((c)*24+(p))*68 + (b))
#define WB(buf,p,j)   (6528 + (buf)*768 + (p)*32 + (j))
#define HS(ph,b,col)  (((ph)*64+(b))*61 + (col))

__device__ __forceinline__ void gload_lds16(const float* g, float* l) {
    __builtin_amdgcn_global_load_lds(
        (const __attribute__((address_space(1))) void*)g,
        (__attribute__((address_space(3))) void*)l, 16, 0, 0);
}

// ---------------------------------------------------------------------------
// Kernel 1 (v14): the v6 structure (best known: 159us at 2 waves/SIMD) with
// __launch_bounds__(256) -- NO second argument. Empirical law R3..R13: the
// 2nd arg w sets BOTH the residency cap (~w waves/SIMD) and the VGPR budget
// (~256/w); the v6 tile needs ~112 regs, so any w>=3 spills and w=2 idles.
// Omitting w: VGPR cap 512 (compiler uses what it needs, ~112-128, no
// spill), runtime residency set by usage: 112 regs -> 4 waves/SIMD, LDS
// 32.25KB -> 4 blocks/CU. Also: v10 W ROW-clamp fix (v6's byte-clamp
// corrupted window 999's last row -> absmax 0.078).
// lane = (bq 0..15, jq 0..3): acc[4 b][8 j][2 c]; per position one wave reads
// 2 b128 x + 2 b128 W for 64 FMA. W via global_load_lds into padded [24][32];
// x reg-staged as 3 float4/thread, issued before compute, committed after.
// ---------------------------------------------------------------------------
__global__ __launch_bounds__(256) void k1(
        const float* __restrict__ x,
        const float* __restrict__ W1, const float* __restrict__ b1,
        const float* __restrict__ W2, const float* __restrict__ b2,
        float* __restrict__ out_base)
{
    __shared__ float smem[8064];   // 32,256 B -> 4 blocks/CU by LDS

    const int n    = blockIdx.x;
    const int t    = threadIdx.x;
    const int wid  = __builtin_amdgcn_readfirstlane(t >> 6);
    const int lane = t & 63;
    const int bq   = lane & 15;        // 4-batch group
    const int jq   = lane >> 4;        // j-quarter
    const int b0   = bq * 4;
    const int j0   = jq * 8;

    float acc[4][8][2];
#pragma unroll
    for (int i = 0; i < 4; ++i)
#pragma unroll
        for (int j = 0; j < 8; ++j) { acc[i][j][0] = 0.f; acc[i][j][1] = 0.f; }

    // x staging: granule = float4 = 2 positions x 2 channels.
    // 64 b * 12 granules = 768 per chunk -> exactly 3 per thread.
    int sb[3], sq[3];
#pragma unroll
    for (int r = 0; r < 3; ++r) {
        const int idx = t + r * 256;
        sb[r] = idx / 12;
        sq[r] = idx % 12;
    }

    const float4* __restrict__ x4 = reinterpret_cast<const float4*>(x);
    float4 xr[3];

    auto issue_x = [&](int ck) {
#pragma unroll
        for (int r = 0; r < 3; ++r) {
            int gq = ck * 12 + sq[r];          // float4 index within window row
            if (gq > 249) gq = 249;            // last-chunk OOB clamp
            xr[r] = x4[(size_t)sb[r] * 250000u + (size_t)n * 250u + gq];
        }
    };

    auto commit_x = [&](int buf, int ck) {
#pragma unroll
        for (int r = 0; r < 3; ++r) {
            const int p0 = 2 * sq[r], p1 = p0 + 1;
            const bool ok0 = (ck * CK + p0) < 500;
            const bool ok1 = (ck * CK + p1) < 500;
            const int bb = sb[r];
            smem[XB(buf, 0, p0, bb)] = ok0 ? fmaf(2.f, xr[r].x, -1.f) : 0.f;
            smem[XB(buf, 1, p0, bb)] = ok0 ? fmaf(2.f, xr[r].y, -1.f) : 0.f;
            smem[XB(buf, 0, p1, bb)] = ok1 ? fmaf(2.f, xr[r].z, -1.f) : 0.f;
            smem[XB(buf, 1, p1, bb)] = ok1 ? fmaf(2.f, xr[r].w, -1.f) : 0.f;
        }
    };

    // W chunk: 24 rows x 30 floats -> 192 16B granules into padded [24][32].
    // ROW clamp only (v10 fix): tail rows' junk multiplies zeroed x positions;
    // row straddle (floats 30,31) lands in pad slots. The final granule of
    // window 999 reads 8B past the 60MB array -- within page slack (2304B).
    auto issue_w = [&](int ck, int buf) {
        if (t < 192) {
            int gp = ck * CK + (t >> 3);
            if (gp > 499) gp = 499;
            const size_t off = (size_t)n * 15000u + (size_t)gp * 30u
                             + (size_t)(t & 7) * 4u;
            gload_lds16(W1 + off, &smem[WB(buf, 0, 0) + (t & 192) * 4]);
        }
    };

    // ---- prologue ------------------------------------------------------
    issue_w(0, 0);
    issue_x(0);
    commit_x(0, 0);
    __syncthreads();

    // ---- main loop: 1 barrier per chunk --------------------------------
    for (int ck = 0; ck < NCK; ++ck) {
        const int cur = ck & 1, nxt = cur ^ 1;
        const bool pre = (ck < NCK - 1);
        if (pre) {
            issue_w(ck + 1, nxt);
            issue_x(ck + 1);
            __builtin_amdgcn_sched_barrier(0);   // pin issues before compute
        }

        const int pb = wid * 6;
#pragma unroll
        for (int i = 0; i < 6; ++i) {
            const int p = pb + i;
            const float4 xa = *reinterpret_cast<const float4*>(&smem[XB(cur, 0, p, b0)]);
            const float4 xb = *reinterpret_cast<const float4*>(&smem[XB(cur, 1, p, b0)]);
            const float4 w0 = *reinterpret_cast<const float4*>(&smem[WB(cur, p, j0)]);
            const float4 w1 = *reinterpret_cast<const float4*>(&smem[WB(cur, p, j0 + 4)]);
            const float xav[4] = {xa.x, xa.y, xa.z, xa.w};
            const float xbv[4] = {xb.x, xb.y, xb.z, xb.w};
            const float wv[8]  = {w0.x, w0.y, w0.z, w0.w, w1.x, w1.y, w1.z, w1.w};
#pragma unroll
            for (int ii = 0; ii < 4; ++ii)
#pragma unroll
                for (int jj = 0; jj < 8; ++jj) {
                    acc[ii][jj][0] = fmaf(xav[ii], wv[jj], acc[ii][jj][0]);
                    acc[ii][jj][1] = fmaf(xbv[ii], wv[jj], acc[ii][jj][1]);
                }
        }

        if (pre) commit_x(nxt, ck + 1);          // vmcnt waits (covered)
        __syncthreads();                         // drains gload_lds too
    }

    // ---- epilogue: reduce 4 wave-partials into hs[0] + hs[1] ------------
    if (wid < 2) {
#pragma unroll
        for (int ii = 0; ii < 4; ++ii)
#pragma unroll
            for (int jj = 0; jj < 8; ++jj) {
                const int j = j0 + jj;
                if (j < 30) {
                    smem[HS(wid, b0 + ii, j)]      = acc[ii][jj][0];
                    smem[HS(wid, b0 + ii, 30 + j)] = acc[ii][jj][1];
                }
            }
    }
    __syncthreads();
    if (wid >= 2) {
#pragma unroll
        for (int ii = 0; ii < 4; ++ii)
#pragma unroll
            for (int jj = 0; jj < 8; ++jj) {
                const int j = j0 + jj;
                if (j < 30) {
                    smem[HS(wid - 2, b0 + ii, j)]      += acc[ii][jj][0];
                    smem[HS(wid - 2, b0 + ii, 30 + j)] += acc[ii][jj][1];
                }
            }
    }
    __syncthreads();

    {   // bias + relu + two-pass batch stats (64-lane butterflies) + normalize
        const int bb = t & 63;
        const int q2 = t >> 6;
        const int ch = q2 >> 1;
        const int jh = (q2 & 1) * 15;
        const float* __restrict__ b1p = b1 + n * HID + jh;
#pragma unroll
        for (int jj = 0; jj < 15; ++jj) {
            const int col = ch * 30 + jh + jj;
            float v = smem[HS(0, bb, col)] + smem[HS(1, bb, col)] + b1p[jj];
            v = fmaxf(v, 0.f);
            float s = v;
#pragma unroll
            for (int off = 32; off > 0; off >>= 1) s += __shfl_xor(s, off);
            const float mean = s * (1.f / 64.f);
            const float d = v - mean;
            float ss = d * d;
#pragma unroll
            for (int off = 32; off > 0; off >>= 1) ss += __shfl_xor(ss, off);
            const float var = ss * (1.f / 64.f);
            const float rn  = rsqrtf(var + 1e-5f);
            smem[HS(0, bb, col)] = d * rn;
        }
    }
    __syncthreads();

    // ---- GEMM2 + write out_base[b][a][n][c] -----------------------------
    const float* __restrict__ w2p = W2 + (size_t)n * (HID * ANC);
    float2* __restrict__ ob2 = reinterpret_cast<float2*>(out_base);
    for (int idx = t; idx < BATCH * ANC; idx += 256) {
        const int bb = idx / 7, a = idx - bb * 7;
        float o0 = b2[n * ANC + a], o1 = o0;
#pragma unroll
        for (int h = 0; h < HID; ++h) {
            const float wv = w2p[h * ANC + a];
            o0 = fmaf(smem[HS(0, bb, h)],      wv, o0);
            o1 = fmaf(smem[HS(0, bb, 30 + h)], wv, o1);
        }
        ob2[((size_t)bb * ANC + a) * NWIN + n] = make_float2(o0, o1);
    }
}

// ---------------------------------------------------------------------------
// Kernel 2: softmax over ANC + reflect-pad + conv (2 needed output columns)
// via sum/diff factorization. (256,2): 128-reg budget, no spill.
// ---------------------------------------------------------------------------
__global__ __launch_bounds__(256, 2) void k2(
        const float* __restrict__ out_base,
        const float* __restrict__ conv_w, const float* __restrict__ conv_b,
        float* __restrict__ out_smooth)
{
    __shared__ float2 sdl[199 * ANC];
    __shared__ float2 wael[ANC * ANC * KS];

    const int bidx = blockIdx.x;
    const int b  = bidx >> 3;
    const int ht = bidx & 7;
    const int h0 = ht * 125;
    const int t  = threadIdx.x;

    const float2* __restrict__ cw2 = reinterpret_cast<const float2*>(conv_w);
    for (int idx = t; idx < ANC * ANC * KS; idx += 256) {
        const float2 w = cw2[idx];
        wael[idx] = make_float2(w.x + w.y, w.x - w.y);
    }

    if (t < 199) {
        const int hglob = h0 - PADH + t;
        const int hm = hglob < 0 ? -hglob
                     : (hglob >= NWIN ? 2 * NWIN - 2 - hglob : hglob);
        float p[2][ANC];
#pragma unroll
        for (int c = 0; c < 2; ++c) {
            float v[ANC];
            float m = -1e30f;
#pragma unroll
            for (int a = 0; a < ANC; ++a) {
                v[a] = out_base[(((size_t)b * ANC + a) * NWIN + hm) * 2 + c];
                m = fmaxf(m, v[a]);
            }
            float s = 0.f;
#pragma unroll
            for (int a = 0; a < ANC; ++a) { v[a] = __expf(v[a] - m); s += v[a]; }
            const float inv = 1.f / s;
#pragma unroll
            for (int a = 0; a < ANC; ++a) p[c][a] = v[a] * inv;
        }
#pragma unroll
        for (int a = 0; a < ANC; ++a)
            sdl[t * ANC + a] = make_float2(p[0][a] + p[1][a], p[0][a] - p[1][a]);
    }
    __syncthreads();

    for (int idx = t; idx < ANC * 125; idx += 256) {
        const int o  = idx / 125;
        const int hl = idx % 125;
        float sa = 0.f, de = 0.f;
        const float2* __restrict__ wrow = &wael[o * ANC * KS];
#pragma unroll 1
        for (int i = 0; i < ANC; ++i) {
            const float2* __restrict__ sdp = &sdl[hl * ANC + i];
            const float2* __restrict__ wp  = &wrow[i * KS];
#pragma unroll 5
            for (int kh = 0; kh < KS; ++kh) {
                const float2 sd = sdp[kh * ANC];
                const float2 we = wp[kh];
                sa = fmaf(sd.x, we.x, sa);
                de = fmaf(sd.y, we.y, de);
            }
        }
        const float cb = conv_b[o];
        const float o0 = 0.5f * (sa - de) + cb;
        const float o1 = 0.5f * (sa + de) + cb;
        const size_t base = (((size_t)b * ANC + o) * NWIN + (h0 + hl)) * 2;
        out_smooth[base + 0] = o0;
        out_smooth[base + 1] = o1;
    }
}

extern "C" void kernel_launch(void* const* d_in, const int* in_sizes, int n_in,
                              void* d_out, int out_size, void* d_ws, size_t ws_size,
                              hipStream_t stream)
{
    const float* x      = (const float*)d_in[0];
    const float* W1     = (const float*)d_in[1];
    const float* b1     = (const float*)d_in[2];
    const float* W2     = (const float*)d_in[3];
    const float* b2     = (const float*)d_in[4];
    const float* conv_w = (const float*)d_in[5];
    const float* conv_b = (const float*)d_in[6];
    float* out = (float*)d_out;

    k1<<<dim3(NWIN), dim3(256), 0, stream>>>(x, W1, b1, W2, b2, out);
    k2<<<dim3(BATCH * 8), dim3(256), 0, stream>>>(out, conv_w, conv_b,
                                                  out + OBASE_ELEMS);
}

// Round 17
// 166.050 us; speedup vs baseline: 2.8332x; 1.0032x over previous
//
#include <hip/hip_runtime.h>

#define NWIN 1000
#define WIN  500
#define HID  30
#define ANC  7
#define BATCH 64
#define KS   75
#define PADH 37
#define OBASE_ELEMS (BATCH*ANC*NWIN*2)   // 896000

// k1 geometry: 21 chunks of 24 positions (504 padded; 500 real)
#define CK   24
#define NCK  21

// LDS float-offset map (flat array; epilogue overlays the front)
//   x [2 buf][c][24 pos][68] : buf*3264 + (c*24+p)*68 + b    [0 .. 6527]
//   W [4 buf][24 pos][32]    : 6528 + buf*768 + p*32 + j     [6528 .. 9599]
//   hs[ph][64 b][61]         : (ph*64+b)*61 + col (overlay)  [0 .. 7807]
#define XB(buf,c,p,b) ((buf)*3264 + ((c)*24+(p))*68 + (b))
#define WB4(buf,p,j)  (6528 + (buf)*768 + (p)*32 + (j))
#define HS(ph,b,col)  (((ph)*64+(b))*61 + (col))

__device__ __forceinline__ void gload_lds16(const float* g, float* l) {
    __builtin_amdgcn_global_load_lds(
        (const __attribute__((address_space(1))) void*)g,
        (__attribute__((address_space(3))) void*)l, 16, 0, 0);
}

// ---------------------------------------------------------------------------
// Kernel 1 (v15): v14 structure + COUNTED-vmcnt pipeline (guide T4).
// Diagnosis R15: at VGPR 112 the HW gives 2 waves/SIMD (law: waves/SIMD ~
// floor(256/VGPR), fits all 10 prior runs); the 69% idle is the per-chunk
// __syncthreads() vmcnt(0) drain (one full HBM latency per chunk).
// Fix: W prefetch 2 chunks deep into 4 LDS buffers; issue_w wave-uniform
// (t%192; wave 3 duplicates wave 0's granules -> static vmcnt). Per iter the
// per-wave vmem queue is [W(k+1), x3(k+1), W(k+2)]: commit_x's implicit wait
// on x drains W(k+1) (oldest-first), leaving W(k+2) in flight; then only
// lgkmcnt(0) + RAW s_barrier (no vmcnt0 drain). Last 2 iters peeled so each
// static path has exact counts.
// ---------------------------------------------------------------------------
__global__ __launch_bounds__(256) void k1(
        const float* __restrict__ x,
        const float* __restrict__ W1, const float* __restrict__ b1,
        const float* __restrict__ W2, const float* __restrict__ b2,
        float* __restrict__ out_base)
{
    __shared__ float smem[9600];   // 38,400 B

    const int n    = blockIdx.x;
    const int t    = threadIdx.x;
    const int wid  = __builtin_amdgcn_readfirstlane(t >> 6);
    const int lane = t & 63;
    const int bq   = lane & 15;        // 4-batch group
    const int jq   = lane >> 4;        // j-quarter
    const int b0   = bq * 4;
    const int j0   = jq * 8;

    float acc[4][8][2];
#pragma unroll
    for (int i = 0; i < 4; ++i)
#pragma unroll
        for (int j = 0; j < 8; ++j) { acc[i][j][0] = 0.f; acc[i][j][1] = 0.f; }

    // x staging: granule = float4 = 2 positions x 2 channels.
    // 64 b * 12 granules = 768 per chunk -> exactly 3 per thread.
    int sb[3], sq[3];
#pragma unroll
    for (int r = 0; r < 3; ++r) {
        const int idx = t + r * 256;
        sb[r] = idx / 12;
        sq[r] = idx % 12;
    }

    const float4* __restrict__ x4 = reinterpret_cast<const float4*>(x);
    float4 xr[3];

    auto issue_x = [&](int ck) {
#pragma unroll
        for (int r = 0; r < 3; ++r) {
            int gq = ck * 12 + sq[r];          // float4 index within window row
            if (gq > 249) gq = 249;            // last-chunk OOB clamp
            xr[r] = x4[(size_t)sb[r] * 250000u + (size_t)n * 250u + gq];
        }
    };

    auto commit_x = [&](int buf, int ck) {
#pragma unroll
        for (int r = 0; r < 3; ++r) {
            const int p0 = 2 * sq[r], p1 = p0 + 1;
            const bool ok0 = (ck * CK + p0) < 500;
            const bool ok1 = (ck * CK + p1) < 500;
            const int bb = sb[r];
            smem[XB(buf, 0, p0, bb)] = ok0 ? fmaf(2.f, xr[r].x, -1.f) : 0.f;
            smem[XB(buf, 1, p0, bb)] = ok0 ? fmaf(2.f, xr[r].y, -1.f) : 0.f;
            smem[XB(buf, 0, p1, bb)] = ok1 ? fmaf(2.f, xr[r].z, -1.f) : 0.f;
            smem[XB(buf, 1, p1, bb)] = ok1 ? fmaf(2.f, xr[r].w, -1.f) : 0.f;
        }
    };

    // W chunk: 24 rows x 30 floats -> 192 16B granules into padded [24][32].
    // WAVE-UNIFORM: granule g = t%192 (wave 3 duplicates wave 0's granules --
    // same source, same dest, benign) so every wave issues exactly 1 vmem op
    // and the compiler's static vmcnt bookkeeping is uniform.
    // ROW clamp only: tail rows' junk multiplies zeroed x positions; the
    // row straddle (floats 30,31) lands in pad slots.
    auto issue_w = [&](int ck, int buf) {
        const int g = (t < 192) ? t : (t - 192);
        int gp = ck * CK + (g >> 3);
        if (gp > 499) gp = 499;
        const size_t off = (size_t)n * 15000u + (size_t)gp * 30u
                         + (size_t)(g & 7) * 4u;
        gload_lds16(W1 + off, &smem[6528 + buf * 768 + (g & 192) * 4]);
    };

    auto compute = [&](int cur, int wc) {
        const int pb = wid * 6;
#pragma unroll
        for (int i = 0; i < 6; ++i) {
            const int p = pb + i;
            const float4 xa = *reinterpret_cast<const float4*>(&smem[XB(cur, 0, p, b0)]);
            const float4 xb = *reinterpret_cast<const float4*>(&smem[XB(cur, 1, p, b0)]);
            const float4 w0 = *reinterpret_cast<const float4*>(&smem[WB4(wc, p, j0)]);
            const float4 w1 = *reinterpret_cast<const float4*>(&smem[WB4(wc, p, j0 + 4)]);
            const float xav[4] = {xa.x, xa.y, xa.z, xa.w};
            const float xbv[4] = {xb.x, xb.y, xb.z, xb.w};
            const float wv[8]  = {w0.x, w0.y, w0.z, w0.w, w1.x, w1.y, w1.z, w1.w};
#pragma unroll
            for (int ii = 0; ii < 4; ++ii)
#pragma unroll
                for (int jj = 0; jj < 8; ++jj) {
                    acc[ii][jj][0] = fmaf(xav[ii], wv[jj], acc[ii][jj][0]);
                    acc[ii][jj][1] = fmaf(xbv[ii], wv[jj], acc[ii][jj][1]);
                }
        }
    };

    // ---- prologue: x(0) committed; W(0) drained; W(1) left in flight -----
    issue_x(0);                    // queue: x3(0)
    issue_w(0, 0);                 // queue: x3(0), W(0)
    commit_x(0, 0);                // implicit wait -> x done, W(0) may remain
    issue_w(1, 1);                 // queue: W(0), W(1)
    asm volatile("s_waitcnt vmcnt(1) lgkmcnt(0)" ::: "memory");  // W(0)+writes done
    __builtin_amdgcn_s_barrier();

    // ---- main loop k = 0..NCK-3 (uniform: 3x + 1W issued per wave) -------
    for (int ck = 0; ck < NCK - 2; ++ck) {
        const int cur = ck & 1;
        issue_x(ck + 1);                       // x3(k+1)
        issue_w(ck + 2, (ck + 2) & 3);         // W(k+2)
        __builtin_amdgcn_sched_barrier(0);     // pin issues before compute

        compute(cur, ck & 3);

        commit_x((ck + 1) & 1, ck + 1);        // implicit vmcnt drains W(k+1),x3
        asm volatile("s_waitcnt lgkmcnt(0)" ::: "memory");  // ds_writes visible
        __builtin_amdgcn_s_barrier();          // W(k+2) stays in flight
    }

    // ---- peel k = NCK-2: no W issue -> commit drains everything ----------
    {
        issue_x(NCK - 1);
        __builtin_amdgcn_sched_barrier(0);
        compute((NCK - 2) & 1, (NCK - 2) & 3);
        commit_x((NCK - 1) & 1, NCK - 1);      // implicit vmcnt(0) path
        asm volatile("s_waitcnt lgkmcnt(0)" ::: "memory");
        __builtin_amdgcn_s_barrier();
    }
    // ---- peel k = NCK-1: pure compute ------------------------------------
    compute((NCK - 1) & 1, (NCK - 1) & 3);
    __syncthreads();

    // ---- epilogue: reduce 4 wave-partials into hs[0] + hs[1] ------------
    if (wid < 2) {
#pragma unroll
        for (int ii = 0; ii < 4; ++ii)
#pragma unroll
            for (int jj = 0; jj < 8; ++jj) {
                const int j = j0 + jj;
                if (j < 30) {
                    smem[HS(wid, b0 + ii, j)]      = acc[ii][jj][0];
                    smem[HS(wid, b0 + ii, 30 + j)] = acc[ii][jj][1];
                }
            }
    }
    __syncthreads();
    if (wid >= 2) {
#pragma unroll
        for (int ii = 0; ii < 4; ++ii)
#pragma unroll
            for (int jj = 0; jj < 8; ++jj) {
                const int j = j0 + jj;
                if (j < 30) {
                    smem[HS(wid - 2, b0 + ii, j)]      += acc[ii][jj][0];
                    smem[HS(wid - 2, b0 + ii, 30 + j)] += acc[ii][jj][1];
                }
            }
    }
    __syncthreads();

    {   // bias + relu + two-pass batch stats (64-lane butterflies) + normalize
        const int bb = t & 63;
        const int q2 = t >> 6;
        const int ch = q2 >> 1;
        const int jh = (q2 & 1) * 15;
        const float* __restrict__ b1p = b1 + n * HID + jh;
#pragma unroll
        for (int jj = 0; jj < 15; ++jj) {
            const int col = ch * 30 + jh + jj;
            float v = smem[HS(0, bb, col)] + smem[HS(1, bb, col)] + b1p[jj];
            v = fmaxf(v, 0.f);
            float s = v;
#pragma unroll
            for (int off = 32; off > 0; off >>= 1) s += __shfl_xor(s, off);
            const float mean = s * (1.f / 64.f);
            const float d = v - mean;
            float ss = d * d;
#pragma unroll
            for (int off = 32; off > 0; off >>= 1) ss += __shfl_xor(ss, off);
            const float var = ss * (1.f / 64.f);
            const float rn  = rsqrtf(var + 1e-5f);
            smem[HS(0, bb, col)] = d * rn;
        }
    }
    __syncthreads();

    // ---- GEMM2 + write out_base[b][a][n][c] -----------------------------
    const float* __restrict__ w2p = W2 + (size_t)n * (HID * ANC);
    float2* __restrict__ ob2 = reinterpret_cast<float2*>(out_base);
    for (int idx = t; idx < BATCH * ANC; idx += 256) {
        const int bb = idx / 7, a = idx - bb * 7;
        float o0 = b2[n * ANC + a], o1 = o0;
#pragma unroll
        for (int h = 0; h < HID; ++h) {
            const float wv = w2p[h * ANC + a];
            o0 = fmaf(smem[HS(0, bb, h)],      wv, o0);
            o1 = fmaf(smem[HS(0, bb, 30 + h)], wv, o1);
        }
        ob2[((size_t)bb * ANC + a) * NWIN + n] = make_float2(o0, o1);
    }
}

// ---------------------------------------------------------------------------
// Kernel 2: softmax over ANC + reflect-pad + conv (2 needed output columns)
// via sum/diff factorization. (256,2): 128-reg budget, no spill.
// ---------------------------------------------------------------------------
__global__ __launch_bounds__(256, 2) void k2(
        const float* __restrict__ out_base,
        const float* __restrict__ conv_w, const float* __restrict__ conv_b,
        float* __restrict__ out_smooth)
{
    __shared__ float2 sdl[199 * ANC];
    __shared__ float2 wael[ANC * ANC * KS];

    const int bidx = blockIdx.x;
    const int b  = bidx >> 3;
    const int ht = bidx & 7;
    const int h0 = ht * 125;
    const int t  = threadIdx.x;

    const float2* __restrict__ cw2 = reinterpret_cast<const float2*>(conv_w);
    for (int idx = t; idx < ANC * ANC * KS; idx += 256) {
        const float2 w = cw2[idx];
        wael[idx] = make_float2(w.x + w.y, w.x - w.y);
    }

    if (t < 199) {
        const int hglob = h0 - PADH + t;
        const int hm = hglob < 0 ? -hglob
                     : (hglob >= NWIN ? 2 * NWIN - 2 - hglob : hglob);
        float p[2][ANC];
#pragma unroll
        for (int c = 0; c < 2; ++c) {
            float v[ANC];
            float m = -1e30f;
#pragma unroll
            for (int a = 0; a < ANC; ++a) {
                v[a] = out_base[(((size_t)b * ANC + a) * NWIN + hm) * 2 + c];
                m = fmaxf(m, v[a]);
            }
            float s = 0.f;
#pragma unroll
            for (int a = 0; a < ANC; ++a) { v[a] = __expf(v[a] - m); s += v[a]; }
            const float inv = 1.f / s;
#pragma unroll
            for (int a = 0; a < ANC; ++a) p[c][a] = v[a] * inv;
        }
#pragma unroll
        for (int a = 0; a < ANC; ++a)
            sdl[t * ANC + a] = make_float2(p[0][a] + p[1][a], p[0][a] - p[1][a]);
    }
    __syncthreads();

    for (int idx = t; idx < ANC * 125; idx += 256) {
        const int o  = idx / 125;
        const int hl = idx % 125;
        float sa = 0.f, de = 0.f;
        const float2* __restrict__ wrow = &wael[o * ANC * KS];
#pragma unroll 1
        for (int i = 0; i < ANC; ++i) {
            const float2* __restrict__ sdp = &sdl[hl * ANC + i];
            const float2* __restrict__ wp  = &wrow[i * KS];
#pragma unroll 5
            for (int kh = 0; kh < KS; ++kh) {
                const float2 sd = sdp[kh * ANC];
                const float2 we = wp[kh];
                sa = fmaf(sd.x, we.x, sa);
                de = fmaf(sd.y, we.y, de);
            }
        }
        const float cb = conv_b[o];
        const float o0 = 0.5f * (sa - de) + cb;
        const float o1 = 0.5f * (sa + de) + cb;
        const size_t base = (((size_t)b * ANC + o) * NWIN + (h0 + hl)) * 2;
        out_smooth[base + 0] = o0;
        out_smooth[base + 1] = o1;
    }
}

extern "C" void kernel_launch(void* const* d_in, const int* in_sizes, int n_in,
                              void* d_out, int out_size, void* d_ws, size_t ws_size,
                              hipStream_t stream)
{
    const float* x      = (const float*)d_in[0];
    const float* W1     = (const float*)d_in[1];
    const float* b1     = (const float*)d_in[2];
    const float* W2     = (const float*)d_in[3];
    const float* b2     = (const float*)d_in[4];
    const float* conv_w = (const float*)d_in[5];
    const float* conv_b = (const float*)d_in[6];
    float* out = (float*)d_out;

    k1<<<dim3(NWIN), dim3(256), 0, stream>>>(x, W1, b1, W2, b2, out);
    k2<<<dim3(BATCH * 8), dim3(256), 0, stream>>>(out, conv_w, conv_b,
                                                  out + OBASE_ELEMS);
}